// Round 12
// baseline (549.880 us; speedup 1.0000x reference)
//
#include <hip/hip_runtime.h>

#define NN 50000
#define NE 1600000
#define DD 128
#define NL 4
#define NG 512
#define NBUK 196    // dst buckets of 256 nodes: ceil(50000/256)
#define NBLK 196    // edge blocks: ceil(NE/8192)
#define EPB 8192    // edges per block in bucket passes
#define HN (NBUK * NBLK)  // 38416
#define HT 151      // ceil(HN/256)
#define SLICE ((size_t)NN * 32)  // one 32-channel pass-slice, in shorts (3.2 MB)

typedef __attribute__((ext_vector_type(8))) short short8;
typedef __attribute__((ext_vector_type(4))) float floatx4;

__device__ __forceinline__ unsigned short f2bf(float f) {
    unsigned int u = __float_as_uint(f);
    u += 0x7fffu + ((u >> 16) & 1u);
    return (unsigned short)(u >> 16);
}
__device__ __forceinline__ float bf2f(unsigned short u) {
    return __uint_as_float(((unsigned int)u) << 16);
}

// ---------- fp32 -> bf16 convert into channel-split layout ----------
// Feature tensors are stored as [pass][node][32ch] (4 slices of 3.2 MB) so the
// aggregation working set per pass fits a single XCD L2 (4 MB). R11 counters:
// monolithic-row gather pinned at ~3.1 TB/s L2-miss path across 4 variants.
__global__ __launch_bounds__(256) void cvt_kernel(const float* __restrict__ x,
                                                  unsigned short* __restrict__ xcs) {
    int t = blockIdx.x * 256 + threadIdx.x;  // [0, NN*16): one 8-ch chunk
    int node = t >> 4, chunk = t & 15;
    int pass = chunk >> 2, sub = chunk & 3;
    const float* xp = x + (size_t)node * DD + chunk * 8;
    float4 f0 = *(const float4*)xp;
    float4 f1 = *(const float4*)(xp + 4);
    uint4 o;
    o.x = (unsigned int)f2bf(f0.x) | ((unsigned int)f2bf(f0.y) << 16);
    o.y = (unsigned int)f2bf(f0.z) | ((unsigned int)f2bf(f0.w) << 16);
    o.z = (unsigned int)f2bf(f1.x) | ((unsigned int)f2bf(f1.y) << 16);
    o.w = (unsigned int)f2bf(f1.z) | ((unsigned int)f2bf(f1.w) << 16);
    *(uint4*)(xcs + (size_t)pass * SLICE + (size_t)node * 32 + sub * 8) = o;
}

// ---------- CSR build: LDS-only counting sort (ZERO global atomics) ----------
// R6/R7: global atomic RMWs execute memory-side on gfx950 (~35 B write-through
// + serialized round trip each, scope hints ignored). Bucket sort, LDS atomics.

__global__ __launch_bounds__(512) void bhist_kernel(const int* __restrict__ dst,
                                                    int* __restrict__ hist) {
    __shared__ int h[NBUK];
    int tid = threadIdx.x;
    for (int i = tid; i < NBUK; i += 512) h[i] = 0;
    __syncthreads();
    int base = blockIdx.x * EPB;
#pragma unroll
    for (int it = 0; it < EPB / 512; it++) {
        int e = base + it * 512 + tid;
        if (e < NE) atomicAdd(&h[dst[e] >> 8], 1);
    }
    __syncthreads();
    for (int i = tid; i < NBUK; i += 512) hist[i * NBLK + blockIdx.x] = h[i];
}

__global__ __launch_bounds__(256) void sum_tiles_kernel(const int* __restrict__ in,
                                                        int* __restrict__ tsum, int n) {
    int i = blockIdx.x * 256 + threadIdx.x;
    __shared__ int s[256];
    s[threadIdx.x] = (i < n) ? in[i] : 0;
    __syncthreads();
    for (int off = 128; off > 0; off >>= 1) {
        if (threadIdx.x < off) s[threadIdx.x] += s[threadIdx.x + off];
        __syncthreads();
    }
    if (threadIdx.x == 0) tsum[blockIdx.x] = s[0];
}

__global__ __launch_bounds__(256) void scan_tiles_kernel(const int* __restrict__ tsum,
                                                         int* __restrict__ toff, int ntiles) {
    int t = threadIdx.x;
    __shared__ int s[256];
    int v = (t < ntiles) ? tsum[t] : 0;
    s[t] = v;
    __syncthreads();
    for (int off = 1; off < 256; off <<= 1) {
        int u = (t >= off) ? s[t - off] : 0;
        __syncthreads();
        s[t] += u;
        __syncthreads();
    }
    if (t < ntiles) toff[t] = s[t] - v;
}

__global__ __launch_bounds__(256) void scan_out_kernel(const int* __restrict__ in,
                                                       const int* __restrict__ toff,
                                                       int* __restrict__ out, int n) {
    int i = blockIdx.x * 256 + threadIdx.x;
    int t = threadIdx.x;
    int v = (i < n) ? in[i] : 0;
    __shared__ int s[256];
    s[t] = v;
    __syncthreads();
    for (int off = 1; off < 256; off <<= 1) {
        int u = (t >= off) ? s[t - off] : 0;
        __syncthreads();
        s[t] += u;
        __syncthreads();
    }
    if (i < n) out[i] = toff[blockIdx.x] + s[t] - v;
}

// Pass 3: scatter edges into bucket-sorted ebuf, PACKED: (src<<8)|(dst&255).
__global__ __launch_bounds__(512) void bscatter_kernel(const int* __restrict__ src,
                                                       const int* __restrict__ dst,
                                                       const int* __restrict__ bkoff,
                                                       int* __restrict__ ebuf) {
    __shared__ int h[NBUK];
    int tid = threadIdx.x;
    for (int i = tid; i < NBUK; i += 512) h[i] = 0;
    __syncthreads();
    int base = blockIdx.x * EPB;
#pragma unroll
    for (int it = 0; it < EPB / 512; it++) {
        int e = base + it * 512 + tid;
        if (e < NE) {
            int d = dst[e];
            int bu = d >> 8;
            int p = atomicAdd(&h[bu], 1);
            ebuf[bkoff[bu * NBLK + blockIdx.x] + p] = (src[e] << 8) | (d & 255);
        }
    }
}

// Pass 4: one block per bucket: LDS histogram over dst&255 -> LDS scan
// -> rowptr for this bucket's nodes + scatter src into final CSR col.
__global__ __launch_bounds__(256) void bucket_csr_kernel(const int* __restrict__ ebuf,
                                                         const int* __restrict__ bkoff,
                                                         int* __restrict__ rowptr,
                                                         int* __restrict__ col) {
    __shared__ int cnt[256], exc[256], c2[256];
    int b = blockIdx.x, tid = threadIdx.x;
    int segstart = bkoff[b * NBLK];
    int segend = (b < NBUK - 1) ? bkoff[(b + 1) * NBLK] : NE;
    cnt[tid] = 0;
    c2[tid] = 0;
    __syncthreads();
    for (int i = segstart + tid; i < segend; i += 256)
        atomicAdd(&cnt[ebuf[i] & 255], 1);
    __syncthreads();
    int v = cnt[tid];
    exc[tid] = v;
    __syncthreads();
    for (int off = 1; off < 256; off <<= 1) {
        int u = (tid >= off) ? exc[tid - off] : 0;
        __syncthreads();
        exc[tid] += u;
        __syncthreads();
    }
    int excl = exc[tid] - v;  // exclusive prefix
    exc[tid] = excl;          // own-slot rewrite; others read only after barrier
    int node = (b << 8) + tid;
    if (node <= NN) rowptr[node] = segstart + excl;
    __syncthreads();
    for (int i = segstart + tid; i < segend; i += 256) {
        int ev = ebuf[i];
        int low = ev & 255;
        int p = atomicAdd(&c2[low], 1);
        col[segstart + exc[low] + p] = ((unsigned)ev) >> 8;
    }
}

// ---------- weight prep: fp32 [l][k][n] -> bf16 transposed [l][n][k] ----------
__global__ __launch_bounds__(256) void prep_kernel(const float* __restrict__ Ws1,
                                                   const float* __restrict__ Ws2,
                                                   unsigned short* __restrict__ W1T,
                                                   unsigned short* __restrict__ W2T) {
    int idx = blockIdx.x * 256 + threadIdx.x;  // [0, NL*DD*DD)
    int l = idx >> 14;
    int rem = idx & 16383;
    int k = rem >> 7;
    int n = rem & 127;
    int o = (l << 14) + (n << 7) + k;
    W1T[o] = f2bf(Ws1[idx]);
    W2T[o] = f2bf(Ws2[idx]);
}

// ---------- aggregation, channel-split: one 32-ch pass per launch ----------
// 4 lanes/node (uint4 = 8 bf16 each), 64 nodes/block; fp32 accum; x8 edge unroll.
// Separate launches per pass => stream-order serialization keeps the live slice
// at 3.2 MB (< 4 MB XCD L2). Grid-fused passes would co-reside and re-thrash.
__global__ __launch_bounds__(256) void agg_cs_kernel(const unsigned short* __restrict__ xcs,
                                                     const int* __restrict__ rowptr,
                                                     const int* __restrict__ col,
                                                     unsigned short* __restrict__ hcs,
                                                     int pass) {
    int node = blockIdx.x * 64 + (threadIdx.x >> 2);
    int lane = threadIdx.x & 3;
    if (node >= NN) return;
    const uint4* base = (const uint4*)(xcs + (size_t)pass * SLICE);
    float a[8];
    {
        uint4 v = base[node * 4 + lane];
        a[0] = __uint_as_float(v.x << 16); a[1] = __uint_as_float(v.x & 0xFFFF0000u);
        a[2] = __uint_as_float(v.y << 16); a[3] = __uint_as_float(v.y & 0xFFFF0000u);
        a[4] = __uint_as_float(v.z << 16); a[5] = __uint_as_float(v.z & 0xFFFF0000u);
        a[6] = __uint_as_float(v.w << 16); a[7] = __uint_as_float(v.w & 0xFFFF0000u);
    }
    int s = rowptr[node], e = rowptr[node + 1];
    int i = s;
    for (; i + 8 <= e; i += 8) {
        uint4 v0 = base[col[i] * 4 + lane];
        uint4 v1 = base[col[i + 1] * 4 + lane];
        uint4 v2 = base[col[i + 2] * 4 + lane];
        uint4 v3 = base[col[i + 3] * 4 + lane];
        uint4 v4 = base[col[i + 4] * 4 + lane];
        uint4 v5 = base[col[i + 5] * 4 + lane];
        uint4 v6 = base[col[i + 6] * 4 + lane];
        uint4 v7 = base[col[i + 7] * 4 + lane];
#define ACC(V)                                                            \
        a[0] += __uint_as_float(V.x << 16); a[1] += __uint_as_float(V.x & 0xFFFF0000u); \
        a[2] += __uint_as_float(V.y << 16); a[3] += __uint_as_float(V.y & 0xFFFF0000u); \
        a[4] += __uint_as_float(V.z << 16); a[5] += __uint_as_float(V.z & 0xFFFF0000u); \
        a[6] += __uint_as_float(V.w << 16); a[7] += __uint_as_float(V.w & 0xFFFF0000u)
        ACC(v0); ACC(v1); ACC(v2); ACC(v3); ACC(v4); ACC(v5); ACC(v6); ACC(v7);
    }
    for (; i < e; i++) {
        uint4 v = base[col[i] * 4 + lane];
        ACC(v);
    }
#undef ACC
    uint4 o;
    o.x = (unsigned int)f2bf(a[0]) | ((unsigned int)f2bf(a[1]) << 16);
    o.y = (unsigned int)f2bf(a[2]) | ((unsigned int)f2bf(a[3]) << 16);
    o.z = (unsigned int)f2bf(a[4]) | ((unsigned int)f2bf(a[5]) << 16);
    o.w = (unsigned int)f2bf(a[6]) | ((unsigned int)f2bf(a[7]) << 16);
    ((uint4*)(hcs + (size_t)pass * SLICE))[node * 4 + lane] = o;
}

// ---------- GEMM: O = [relu](A@WT^T + bias), 128 rows x 64 cols per block ----------
// W-half staged in LDS (R11 win). A and O are channel-split: MFMA k-step kk is
// exactly pass kk, so A-fragments stay contiguous 16 B loads within a slice.
#define WS_STR 136
template <bool RELU>
__global__ __launch_bounds__(256) void gemm_kernel(const unsigned short* __restrict__ A,
                                                   const unsigned short* __restrict__ WT,
                                                   const float* __restrict__ bias,
                                                   unsigned short* __restrict__ O) {
    __shared__ unsigned short Ws[64 * WS_STR];
    int bx = blockIdx.x;
    int m = bx >> 1, nh = bx & 1;
    int tid = threadIdx.x;

    // stage W-half: rows [nh*64, nh*64+64) of WT ([n][k], 256 B = 16 uint4 each)
    const uint4* wg = (const uint4*)(WT + (size_t)(nh * 64) * DD);  // 1024 uint4
#pragma unroll
    for (int it = 0; it < 4; it++) {
        int idx = it * 256 + tid;
        int n = idx >> 4, kc = idx & 15;
        *(uint4*)&Ws[n * WS_STR + kc * 8] = wg[idx];
    }
    __syncthreads();

    int w = tid >> 6;
    int lane = tid & 63;
    int quad = lane >> 4;
    int li = lane & 15;
    int rowb = m * 128 + w * 32;

    floatx4 acc[2][4];
#pragma unroll
    for (int mi = 0; mi < 2; mi++)
#pragma unroll
        for (int tn = 0; tn < 4; tn++) acc[mi][tn] = (floatx4){0.f, 0.f, 0.f, 0.f};

#pragma unroll
    for (int kk = 0; kk < 4; kk++) {
        int k0 = kk * 32 + quad * 8;
        short8 af[2];
#pragma unroll
        for (int mi = 0; mi < 2; mi++) {
            int ar = rowb + mi * 16 + li;
            af[mi] = (ar < NN)
                ? *(const short8*)(A + (size_t)kk * SLICE + (size_t)ar * 32 + quad * 8)
                : (short8){0, 0, 0, 0, 0, 0, 0, 0};
        }
#pragma unroll
        for (int tn = 0; tn < 4; tn++) {
            short8 bf = *(const short8*)&Ws[(tn * 16 + li) * WS_STR + k0];
            acc[0][tn] = __builtin_amdgcn_mfma_f32_16x16x32_bf16(af[0], bf, acc[0][tn], 0, 0, 0);
            acc[1][tn] = __builtin_amdgcn_mfma_f32_16x16x32_bf16(af[1], bf, acc[1][tn], 0, 0, 0);
        }
        (void)k0;
    }
#pragma unroll
    for (int tn = 0; tn < 4; tn++) {
        int colg = nh * 64 + tn * 16 + li;
        float bv = bias[colg];
        size_t obase = (size_t)(colg >> 5) * SLICE + (colg & 31);
#pragma unroll
        for (int mi = 0; mi < 2; mi++) {
#pragma unroll
            for (int r = 0; r < 4; r++) {
                int grow = rowb + mi * 16 + quad * 4 + r;
                if (grow < NN) {
                    float v = acc[mi][tn][r] + bv;
                    if (RELU) v = fmaxf(v, 0.f);
                    O[obase + (size_t)grow * 32] = f2bf(v);
                }
            }
        }
    }
}

// ---------- global add pool (channel-split input) ----------
__global__ __launch_bounds__(128) void pool_kernel(const unsigned short* __restrict__ x,
                                                   const int* __restrict__ batch,
                                                   float* __restrict__ out) {
    int g = blockIdx.x;
    int lo = 0, hi = NN;
    while (lo < hi) { int mid = (lo + hi) >> 1; if (batch[mid] < g) lo = mid + 1; else hi = mid; }
    int s = lo;
    hi = NN;
    while (lo < hi) { int mid = (lo + hi) >> 1; if (batch[mid] < g + 1) lo = mid + 1; else hi = mid; }
    int e = lo;
    int d = threadIdx.x;
    size_t base = (size_t)(d >> 5) * SLICE + (d & 31);
    float acc = 0.f;
    for (int i = s; i < e; i++) acc += bf2f(x[base + (size_t)i * 32]);
    out[g * DD + d] = acc;
}

extern "C" void kernel_launch(void* const* d_in, const int* in_sizes, int n_in,
                              void* d_out, int out_size, void* d_ws, size_t ws_size,
                              hipStream_t stream) {
    const float* x0 = (const float*)d_in[0];
    const int* edge = (const int*)d_in[1];
    const int* batch = (const int*)d_in[2];
    const float* Ws1 = (const float*)d_in[3];
    const float* bs1 = (const float*)d_in[4];
    const float* Ws2 = (const float*)d_in[5];
    const float* bs2 = (const float*)d_in[6];
    float* out = (float*)d_out;
    const int* src = edge;
    const int* dst = edge + NE;

    char* ws = (char*)d_ws;
    size_t off = 0;
    auto alloc = [&](size_t bytes) {
        void* p = ws + off;
        off += (bytes + 255) & ~(size_t)255;
        return p;
    };
    unsigned short* x0bf = (unsigned short*)alloc((size_t)NN * DD * 2);
    unsigned short* xA = (unsigned short*)alloc((size_t)NN * DD * 2);
    unsigned short* xB = (unsigned short*)alloc((size_t)NN * DD * 2);
    unsigned short* hpre = (unsigned short*)alloc((size_t)NN * DD * 2);
    unsigned short* Hbuf = (unsigned short*)alloc((size_t)NN * DD * 2);
    int* col = (int*)alloc((size_t)NE * 4);
    int* ebuf = (int*)alloc((size_t)NE * 4);
    int* hist = (int*)alloc((size_t)HN * 4);
    int* bkoff = (int*)alloc((size_t)HN * 4);
    int* tsum = (int*)alloc((size_t)HT * 4);
    int* toff = (int*)alloc((size_t)HT * 4);
    int* rowptr = (int*)alloc((size_t)(NN + 1) * 4);
    unsigned short* W1T = (unsigned short*)alloc((size_t)NL * DD * DD * 2);
    unsigned short* W2T = (unsigned short*)alloc((size_t)NL * DD * DD * 2);

    cvt_kernel<<<(NN * 16) / 256, 256, 0, stream>>>(x0, x0bf);
    bhist_kernel<<<NBLK, 512, 0, stream>>>(dst, hist);
    sum_tiles_kernel<<<HT, 256, 0, stream>>>(hist, tsum, HN);
    scan_tiles_kernel<<<1, 256, 0, stream>>>(tsum, toff, HT);
    scan_out_kernel<<<HT, 256, 0, stream>>>(hist, toff, bkoff, HN);
    bscatter_kernel<<<NBLK, 512, 0, stream>>>(src, dst, bkoff, ebuf);
    bucket_csr_kernel<<<NBUK, 256, 0, stream>>>(ebuf, bkoff, rowptr, col);
    prep_kernel<<<(NL * DD * DD) / 256, 256, 0, stream>>>(Ws1, Ws2, W1T, W2T);

    const unsigned short* xin = x0bf;
    unsigned short* bufs[2] = {xA, xB};
    const int agg_grid = (NN + 63) / 64;         // 782
    const int gemm_grid = ((NN + 127) / 128) * 2;  // 782
    for (int l = 0; l < NL; l++) {
        for (int p = 0; p < 4; p++)
            agg_cs_kernel<<<agg_grid, 256, 0, stream>>>(xin, rowptr, col, hpre, p);
        unsigned short* xout = bufs[l & 1];
        gemm_kernel<true><<<gemm_grid, 256, 0, stream>>>(hpre, W1T + l * DD * DD,
                                                         bs1 + l * DD, Hbuf);
        gemm_kernel<false><<<gemm_grid, 256, 0, stream>>>(Hbuf, W2T + l * DD * DD,
                                                          bs2 + l * DD, xout);
        xin = xout;
    }
    pool_kernel<<<NG, 128, 0, stream>>>(xin, batch, out);
}

// Round 14
// 542.254 us; speedup vs baseline: 1.0141x; 1.0141x over previous
//
#include <hip/hip_runtime.h>

#define NN 50000
#define NE 1600000
#define DD 128
#define NL 4
#define NG 512
#define NBUK 196    // dst buckets of 256 nodes: ceil(50000/256)
#define NBLK 196    // edge blocks: ceil(NE/8192)
#define EPB 8192    // edges per block in bucket passes
#define HN (NBUK * NBLK)  // 38416
#define HT 151      // ceil(HN/256)

typedef __attribute__((ext_vector_type(8))) short short8;
typedef __attribute__((ext_vector_type(4))) float floatx4;
typedef __attribute__((ext_vector_type(4))) unsigned int uintx4;  // clang-native: OK for nontemporal builtins

__device__ __forceinline__ unsigned short f2bf(float f) {
    unsigned int u = __float_as_uint(f);
    u += 0x7fffu + ((u >> 16) & 1u);
    return (unsigned short)(u >> 16);
}
__device__ __forceinline__ float bf2f(unsigned short u) {
    return __uint_as_float(((unsigned int)u) << 16);
}

// ---------- fp32 -> bf16 convert (layer-0 input), monolithic [node][128] ----------
// R12 lesson: channel-split slices don't stay L2-resident (col+write streams evict
// them) and 16 launches cost more than the locality gain. Monolithic rows it is.
__global__ __launch_bounds__(256) void cvt_kernel(const float* __restrict__ x,
                                                  unsigned short* __restrict__ xbf) {
    int idx = blockIdx.x * 256 + threadIdx.x;  // one float4 per thread
    float4 f = ((const float4*)x)[idx];
    ushort4 o;
    o.x = f2bf(f.x); o.y = f2bf(f.y); o.z = f2bf(f.z); o.w = f2bf(f.w);
    ((ushort4*)xbf)[idx] = o;
}

// ---------- CSR build: LDS-only counting sort (ZERO global atomics) ----------
// R6/R7: global atomic RMWs execute memory-side on gfx950 (~35 B write-through
// + serialized round trip each, scope hints ignored). Bucket sort, LDS atomics.

__global__ __launch_bounds__(512) void bhist_kernel(const int* __restrict__ dst,
                                                    int* __restrict__ hist) {
    __shared__ int h[NBUK];
    int tid = threadIdx.x;
    for (int i = tid; i < NBUK; i += 512) h[i] = 0;
    __syncthreads();
    int base = blockIdx.x * EPB;
#pragma unroll
    for (int it = 0; it < EPB / 512; it++) {
        int e = base + it * 512 + tid;
        if (e < NE) atomicAdd(&h[dst[e] >> 8], 1);
    }
    __syncthreads();
    for (int i = tid; i < NBUK; i += 512) hist[i * NBLK + blockIdx.x] = h[i];
}

__global__ __launch_bounds__(256) void sum_tiles_kernel(const int* __restrict__ in,
                                                        int* __restrict__ tsum, int n) {
    int i = blockIdx.x * 256 + threadIdx.x;
    __shared__ int s[256];
    s[threadIdx.x] = (i < n) ? in[i] : 0;
    __syncthreads();
    for (int off = 128; off > 0; off >>= 1) {
        if (threadIdx.x < off) s[threadIdx.x] += s[threadIdx.x + off];
        __syncthreads();
    }
    if (threadIdx.x == 0) tsum[blockIdx.x] = s[0];
}

__global__ __launch_bounds__(256) void scan_tiles_kernel(const int* __restrict__ tsum,
                                                         int* __restrict__ toff, int ntiles) {
    int t = threadIdx.x;
    __shared__ int s[256];
    int v = (t < ntiles) ? tsum[t] : 0;
    s[t] = v;
    __syncthreads();
    for (int off = 1; off < 256; off <<= 1) {
        int u = (t >= off) ? s[t - off] : 0;
        __syncthreads();
        s[t] += u;
        __syncthreads();
    }
    if (t < ntiles) toff[t] = s[t] - v;
}

__global__ __launch_bounds__(256) void scan_out_kernel(const int* __restrict__ in,
                                                       const int* __restrict__ toff,
                                                       int* __restrict__ out, int n) {
    int i = blockIdx.x * 256 + threadIdx.x;
    int t = threadIdx.x;
    int v = (i < n) ? in[i] : 0;
    __shared__ int s[256];
    s[t] = v;
    __syncthreads();
    for (int off = 1; off < 256; off <<= 1) {
        int u = (t >= off) ? s[t - off] : 0;
        __syncthreads();
        s[t] += u;
        __syncthreads();
    }
    if (i < n) out[i] = toff[blockIdx.x] + s[t] - v;
}

// Pass 3: scatter edges into bucket-sorted ebuf, PACKED: (src<<8)|(dst&255).
__global__ __launch_bounds__(512) void bscatter_kernel(const int* __restrict__ src,
                                                       const int* __restrict__ dst,
                                                       const int* __restrict__ bkoff,
                                                       int* __restrict__ ebuf) {
    __shared__ int h[NBUK];
    int tid = threadIdx.x;
    for (int i = tid; i < NBUK; i += 512) h[i] = 0;
    __syncthreads();
    int base = blockIdx.x * EPB;
#pragma unroll
    for (int it = 0; it < EPB / 512; it++) {
        int e = base + it * 512 + tid;
        if (e < NE) {
            int d = dst[e];
            int bu = d >> 8;
            int p = atomicAdd(&h[bu], 1);
            ebuf[bkoff[bu * NBLK + blockIdx.x] + p] = (src[e] << 8) | (d & 255);
        }
    }
}

// Pass 4: one block per bucket: LDS histogram over dst&255 -> LDS scan
// -> rowptr for this bucket's nodes + scatter src into final CSR col.
__global__ __launch_bounds__(256) void bucket_csr_kernel(const int* __restrict__ ebuf,
                                                         const int* __restrict__ bkoff,
                                                         int* __restrict__ rowptr,
                                                         int* __restrict__ col) {
    __shared__ int cnt[256], exc[256], c2[256];
    int b = blockIdx.x, tid = threadIdx.x;
    int segstart = bkoff[b * NBLK];
    int segend = (b < NBUK - 1) ? bkoff[(b + 1) * NBLK] : NE;
    cnt[tid] = 0;
    c2[tid] = 0;
    __syncthreads();
    for (int i = segstart + tid; i < segend; i += 256)
        atomicAdd(&cnt[ebuf[i] & 255], 1);
    __syncthreads();
    int v = cnt[tid];
    exc[tid] = v;
    __syncthreads();
    for (int off = 1; off < 256; off <<= 1) {
        int u = (tid >= off) ? exc[tid - off] : 0;
        __syncthreads();
        exc[tid] += u;
        __syncthreads();
    }
    int excl = exc[tid] - v;  // exclusive prefix
    exc[tid] = excl;          // own-slot rewrite; others read only after barrier
    int node = (b << 8) + tid;
    if (node <= NN) rowptr[node] = segstart + excl;
    __syncthreads();
    for (int i = segstart + tid; i < segend; i += 256) {
        int ev = ebuf[i];
        int low = ev & 255;
        int p = atomicAdd(&c2[low], 1);
        col[segstart + exc[low] + p] = ((unsigned)ev) >> 8;
    }
}

// ---------- weight prep: fp32 [l][k][n] -> bf16 transposed [l][n][k] ----------
__global__ __launch_bounds__(256) void prep_kernel(const float* __restrict__ Ws1,
                                                   const float* __restrict__ Ws2,
                                                   unsigned short* __restrict__ W1T,
                                                   unsigned short* __restrict__ W2T) {
    int idx = blockIdx.x * 256 + threadIdx.x;  // [0, NL*DD*DD)
    int l = idx >> 14;
    int rem = idx & 16383;
    int k = rem >> 7;
    int n = rem & 127;
    int o = (l << 14) + (n << 7) + k;
    W1T[o] = f2bf(Ws1[idx]);
    W2T[o] = f2bf(Ws2[idx]);
}

// ---------- aggregation: hpre[i] = x[i] + sum_{j in N(i)} x[j], bf16 in/out ----------
// Monolithic rows, 16 lanes/node, uintx4 per lane, x8 edge unroll (R11 structure).
// R13: non-temporal col loads + hpre stores — stream-once traffic must not evict
// x (the only L2 reuse target; R12 showed pollution kills residency).
__global__ __launch_bounds__(256) void agg_kernel(const unsigned short* __restrict__ xbf,
                                                  const int* __restrict__ rowptr,
                                                  const int* __restrict__ col,
                                                  unsigned short* __restrict__ hpre) {
    int g = threadIdx.x >> 4;   // 16 node-groups per block
    int lane = threadIdx.x & 15;
    int node = blockIdx.x * 16 + g;  // NN = 3125*16 exactly
    const uintx4* base = (const uintx4*)xbf;
    float a[8];
    {
        uintx4 v = base[node * 16 + lane];
        a[0] = __uint_as_float(v.x << 16); a[1] = __uint_as_float(v.x & 0xFFFF0000u);
        a[2] = __uint_as_float(v.y << 16); a[3] = __uint_as_float(v.y & 0xFFFF0000u);
        a[4] = __uint_as_float(v.z << 16); a[5] = __uint_as_float(v.z & 0xFFFF0000u);
        a[6] = __uint_as_float(v.w << 16); a[7] = __uint_as_float(v.w & 0xFFFF0000u);
    }
    int s = rowptr[node], e = rowptr[node + 1];
    int i = s;
    for (; i + 8 <= e; i += 8) {
        int j0 = __builtin_nontemporal_load(&col[i]);
        int j1 = __builtin_nontemporal_load(&col[i + 1]);
        int j2 = __builtin_nontemporal_load(&col[i + 2]);
        int j3 = __builtin_nontemporal_load(&col[i + 3]);
        int j4 = __builtin_nontemporal_load(&col[i + 4]);
        int j5 = __builtin_nontemporal_load(&col[i + 5]);
        int j6 = __builtin_nontemporal_load(&col[i + 6]);
        int j7 = __builtin_nontemporal_load(&col[i + 7]);
        uintx4 v0 = base[j0 * 16 + lane];
        uintx4 v1 = base[j1 * 16 + lane];
        uintx4 v2 = base[j2 * 16 + lane];
        uintx4 v3 = base[j3 * 16 + lane];
        uintx4 v4 = base[j4 * 16 + lane];
        uintx4 v5 = base[j5 * 16 + lane];
        uintx4 v6 = base[j6 * 16 + lane];
        uintx4 v7 = base[j7 * 16 + lane];
#define ACC(V)                                                            \
        a[0] += __uint_as_float(V.x << 16); a[1] += __uint_as_float(V.x & 0xFFFF0000u); \
        a[2] += __uint_as_float(V.y << 16); a[3] += __uint_as_float(V.y & 0xFFFF0000u); \
        a[4] += __uint_as_float(V.z << 16); a[5] += __uint_as_float(V.z & 0xFFFF0000u); \
        a[6] += __uint_as_float(V.w << 16); a[7] += __uint_as_float(V.w & 0xFFFF0000u)
        ACC(v0); ACC(v1); ACC(v2); ACC(v3); ACC(v4); ACC(v5); ACC(v6); ACC(v7);
    }
    for (; i < e; i++) {
        int j = __builtin_nontemporal_load(&col[i]);
        uintx4 v = base[j * 16 + lane];
        ACC(v);
    }
#undef ACC
    uintx4 o;
    o.x = (unsigned int)f2bf(a[0]) | ((unsigned int)f2bf(a[1]) << 16);
    o.y = (unsigned int)f2bf(a[2]) | ((unsigned int)f2bf(a[3]) << 16);
    o.z = (unsigned int)f2bf(a[4]) | ((unsigned int)f2bf(a[5]) << 16);
    o.w = (unsigned int)f2bf(a[6]) | ((unsigned int)f2bf(a[7]) << 16);
    __builtin_nontemporal_store(o, (uintx4*)hpre + node * 16 + lane);
}

// ---------- GEMM: O = [relu](A@WT^T + bias), 256 rows x 64 cols per block ----------
// W-half staged in LDS (R11 win). R13: 4 m-tiles per wave (was 2) — each staged
// B-fragment now feeds 4 MFMAs; W-staging cost per row halves. Grid 392.
#define WS_STR 136
template <bool RELU>
__global__ __launch_bounds__(256) void gemm_kernel(const unsigned short* __restrict__ A,
                                                   const unsigned short* __restrict__ WT,
                                                   const float* __restrict__ bias,
                                                   unsigned short* __restrict__ O) {
    __shared__ unsigned short Ws[64 * WS_STR];
    int bx = blockIdx.x;
    int m = bx >> 1, nh = bx & 1;
    int tid = threadIdx.x;

    // stage W-half: rows [nh*64, nh*64+64) of WT ([n][k], 256 B = 16 uint4 each)
    const uint4* wg = (const uint4*)(WT + (size_t)(nh * 64) * DD);  // 1024 uint4
#pragma unroll
    for (int it = 0; it < 4; it++) {
        int idx = it * 256 + tid;
        int n = idx >> 4, kc = idx & 15;
        *(uint4*)&Ws[n * WS_STR + kc * 8] = wg[idx];
    }
    __syncthreads();

    int w = tid >> 6;
    int lane = tid & 63;
    int quad = lane >> 4;
    int li = lane & 15;
    int rowb = m * 256 + w * 64;

    floatx4 acc[4][4];
#pragma unroll
    for (int mi = 0; mi < 4; mi++)
#pragma unroll
        for (int tn = 0; tn < 4; tn++) acc[mi][tn] = (floatx4){0.f, 0.f, 0.f, 0.f};

#pragma unroll
    for (int kk = 0; kk < 4; kk++) {
        int k0 = kk * 32 + quad * 8;
        short8 af[4];
#pragma unroll
        for (int mi = 0; mi < 4; mi++) {
            int ar = rowb + mi * 16 + li;
            af[mi] = (ar < NN) ? *(const short8*)(A + (size_t)ar * DD + k0)
                               : (short8){0, 0, 0, 0, 0, 0, 0, 0};
        }
#pragma unroll
        for (int tn = 0; tn < 4; tn++) {
            short8 bf = *(const short8*)&Ws[(tn * 16 + li) * WS_STR + k0];
#pragma unroll
            for (int mi = 0; mi < 4; mi++)
                acc[mi][tn] = __builtin_amdgcn_mfma_f32_16x16x32_bf16(af[mi], bf, acc[mi][tn], 0, 0, 0);
        }
    }
#pragma unroll
    for (int tn = 0; tn < 4; tn++) {
        int colg = nh * 64 + tn * 16 + li;
        float bv = bias[colg];
#pragma unroll
        for (int mi = 0; mi < 4; mi++) {
#pragma unroll
            for (int r = 0; r < 4; r++) {
                int grow = rowb + mi * 16 + quad * 4 + r;
                if (grow < NN) {
                    float v = acc[mi][tn][r] + bv;
                    if (RELU) v = fmaxf(v, 0.f);
                    O[(size_t)grow * DD + colg] = f2bf(v);
                }
            }
        }
    }
}

// ---------- global add pool: batch sorted -> per-graph contiguous range ----------
__global__ __launch_bounds__(128) void pool_kernel(const unsigned short* __restrict__ x,
                                                   const int* __restrict__ batch,
                                                   float* __restrict__ out) {
    int g = blockIdx.x;
    int lo = 0, hi = NN;
    while (lo < hi) { int mid = (lo + hi) >> 1; if (batch[mid] < g) lo = mid + 1; else hi = mid; }
    int s = lo;
    hi = NN;
    while (lo < hi) { int mid = (lo + hi) >> 1; if (batch[mid] < g + 1) lo = mid + 1; else hi = mid; }
    int e = lo;
    int d = threadIdx.x;
    float acc = 0.f;
    for (int i = s; i < e; i++) acc += bf2f(x[(size_t)i * DD + d]);
    out[g * DD + d] = acc;
}

extern "C" void kernel_launch(void* const* d_in, const int* in_sizes, int n_in,
                              void* d_out, int out_size, void* d_ws, size_t ws_size,
                              hipStream_t stream) {
    const float* x0 = (const float*)d_in[0];
    const int* edge = (const int*)d_in[1];
    const int* batch = (const int*)d_in[2];
    const float* Ws1 = (const float*)d_in[3];
    const float* bs1 = (const float*)d_in[4];
    const float* Ws2 = (const float*)d_in[5];
    const float* bs2 = (const float*)d_in[6];
    float* out = (float*)d_out;
    const int* src = edge;
    const int* dst = edge + NE;

    char* ws = (char*)d_ws;
    size_t off = 0;
    auto alloc = [&](size_t bytes) {
        void* p = ws + off;
        off += (bytes + 255) & ~(size_t)255;
        return p;
    };
    unsigned short* x0bf = (unsigned short*)alloc((size_t)NN * DD * 2);
    unsigned short* xA = (unsigned short*)alloc((size_t)NN * DD * 2);
    unsigned short* xB = (unsigned short*)alloc((size_t)NN * DD * 2);
    unsigned short* hpre = (unsigned short*)alloc((size_t)NN * DD * 2);
    unsigned short* Hbuf = (unsigned short*)alloc((size_t)NN * DD * 2);
    int* col = (int*)alloc((size_t)NE * 4);
    int* ebuf = (int*)alloc((size_t)NE * 4);
    int* hist = (int*)alloc((size_t)HN * 4);
    int* bkoff = (int*)alloc((size_t)HN * 4);
    int* tsum = (int*)alloc((size_t)HT * 4);
    int* toff = (int*)alloc((size_t)HT * 4);
    int* rowptr = (int*)alloc((size_t)(NN + 1) * 4);
    unsigned short* W1T = (unsigned short*)alloc((size_t)NL * DD * DD * 2);
    unsigned short* W2T = (unsigned short*)alloc((size_t)NL * DD * DD * 2);

    cvt_kernel<<<(NN * DD / 4) / 256, 256, 0, stream>>>(x0, x0bf);
    bhist_kernel<<<NBLK, 512, 0, stream>>>(dst, hist);
    sum_tiles_kernel<<<HT, 256, 0, stream>>>(hist, tsum, HN);
    scan_tiles_kernel<<<1, 256, 0, stream>>>(tsum, toff, HT);
    scan_out_kernel<<<HT, 256, 0, stream>>>(hist, toff, bkoff, HN);
    bscatter_kernel<<<NBLK, 512, 0, stream>>>(src, dst, bkoff, ebuf);
    bucket_csr_kernel<<<NBUK, 256, 0, stream>>>(ebuf, bkoff, rowptr, col);
    prep_kernel<<<(NL * DD * DD) / 256, 256, 0, stream>>>(Ws1, Ws2, W1T, W2T);

    const unsigned short* xin = x0bf;
    unsigned short* bufs[2] = {xA, xB};
    const int gemm_grid = ((NN + 255) / 256) * 2;  // 392
    for (int l = 0; l < NL; l++) {
        agg_kernel<<<NN / 16, 256, 0, stream>>>(xin, rowptr, col, hpre);
        unsigned short* xout = bufs[l & 1];
        gemm_kernel<true><<<gemm_grid, 256, 0, stream>>>(hpre, W1T + l * DD * DD,
                                                         bs1 + l * DD, Hbuf);
        gemm_kernel<false><<<gemm_grid, 256, 0, stream>>>(Hbuf, W2T + l * DD * DD,
                                                          bs2 + l * DD, xout);
        xin = xout;
    }
    pool_kernel<<<NG, 128, 0, stream>>>(xin, batch, out);
}